// Round 1
// baseline (603.667 us; speedup 1.0000x reference)
//
#include <hip/hip_runtime.h>
#include <math.h>

// Problem constants (from reference setup_inputs: B=16, L=512, timesteps=20).
// timesteps is a device-side scalar we cannot read during graph capture; the
// reference fixes it at 20, so the host loop is hardcoded.
#define BB 16
#define LL 512
#define TS 20
#define TT 64                    // tile edge
#define NT (LL / TT)             // 8 tiles per side
#define NPAIR (NT * (NT + 1) / 2)  // 36 (I<=J) tile pairs
#define BLL (BB * LL * LL)

#define S_CONST 2.19722457733621938f  // log(9)

__device__ __forceinline__ float sgm(float v) { return 1.0f / (1.0f + __expf(-v)); }
__device__ __forceinline__ float ahat_of(float up) {
  return sgm(up) * sgm(2.0f * (up - S_CONST));
}

__device__ __forceinline__ void decode_pair(int p, int& I, int& J) {
  int base = 0, i = 0;
  while (p >= base + (NT - i)) { base += NT - i; ++i; }
  I = i;
  J = i + (p - base);
}

// ---------------------------------------------------------------------------
// k_init: computes (once)
//   u' = sigmoid(2(u-s))*u           (never stored; only w and ah derived)
//   w[i,j]  = -(u'[i,j]+u'[j,i])/2   (constant across steps)
//   ah[i,j] = sigmoid(u')*sigmoid(2(u'-s))
//   rowsum[b,i] = sum_j 0.5*(ah[i,j]^2+ah[j,i]^2)*m[i,j]   (a0 row sums)
// m recomputed on the fly from x. Tile-pair structure for transpose access.
// ---------------------------------------------------------------------------
__global__ __launch_bounds__(256) void k_init(const float* __restrict__ u,
                                              const float* __restrict__ x,
                                              float* __restrict__ w,
                                              float* __restrict__ ah,
                                              float* __restrict__ rowsum) {
  __shared__ float up1[TT][TT + 1];
  __shared__ float up2[TT][TT + 1];
  __shared__ float xr[2][TT][4];  // raw (A,U,C,G) rows for I(0) and J(1) ranges
  __shared__ float xt[2][TT][4];  // transformed (U, A+G, G, C+U) for column side

  int b = blockIdx.x / NPAIR;
  int p = blockIdx.x % NPAIR;
  int I, J;
  decode_pair(p, I, J);
  bool diag = (I == J);
  int tid = threadIdx.x;
  int tx = tid & 15, ty = tid >> 4;

  if (tid < 128) {
    int which = tid >> 6;
    int r = tid & 63;
    int gi = (which ? J : I) * TT + r;
    const float* xp = x + ((b * LL) + gi) * 4;
    float A = xp[0], U = xp[1], C = xp[2], G = xp[3];
    xr[which][r][0] = A; xr[which][r][1] = U; xr[which][r][2] = C; xr[which][r][3] = G;
    xt[which][r][0] = U; xt[which][r][1] = A + G; xt[which][r][2] = G; xt[which][r][3] = C + U;
  }

  float a1r[4][4], a2r[4][4];

  // phase 1: u -> u' (LDS), ah (regs + global)
#pragma unroll
  for (int k = 0; k < 4; ++k) {
    int r = ty + 16 * k;
    {
      int i = I * TT + r;
      int jb = J * TT + 4 * tx;
      int off = (b * LL + i) * LL + jb;
      float4 u4 = *reinterpret_cast<const float4*>(u + off);
      float uu[4] = {u4.x, u4.y, u4.z, u4.w};
      float av[4];
#pragma unroll
      for (int q = 0; q < 4; ++q) {
        float up = sgm(2.0f * (uu[q] - S_CONST)) * uu[q];
        up1[r][4 * tx + q] = up;
        av[q] = ahat_of(up);
        a1r[k][q] = av[q];
      }
      float4 a4 = make_float4(av[0], av[1], av[2], av[3]);
      *reinterpret_cast<float4*>(ah + off) = a4;
    }
    if (!diag) {
      int i = J * TT + r;
      int jb = I * TT + 4 * tx;
      int off = (b * LL + i) * LL + jb;
      float4 u4 = *reinterpret_cast<const float4*>(u + off);
      float uu[4] = {u4.x, u4.y, u4.z, u4.w};
      float av[4];
#pragma unroll
      for (int q = 0; q < 4; ++q) {
        float up = sgm(2.0f * (uu[q] - S_CONST)) * uu[q];
        up2[r][4 * tx + q] = up;
        av[q] = ahat_of(up);
        a2r[k][q] = av[q];
      }
      float4 a4 = make_float4(av[0], av[1], av[2], av[3]);
      *reinterpret_cast<float4*>(ah + off) = a4;
    }
  }
  __syncthreads();

  float (*U2)[TT + 1] = diag ? up1 : up2;

  // phase 2: w tiles + a0 row sums
#pragma unroll
  for (int k = 0; k < 4; ++k) {
    int r = ty + 16 * k;
    {
      int i = I * TT + r;
      int jb = J * TT + 4 * tx;
      int off = (b * LL + i) * LL + jb;
      float wv[4];
      float rs = 0.0f;
#pragma unroll
      for (int q = 0; q < 4; ++q) {
        int c = 4 * tx + q;
        int j = J * TT + c;
        float upT = U2[c][r];
        wv[q] = -0.5f * (up1[r][c] + upT);
        int d = i - j; d = d < 0 ? -d : d;
        float mm = (d <= 3) ? 0.0f
                            : xr[0][r][0] * xt[1][c][0] + xr[0][r][1] * xt[1][c][1] +
                                  xr[0][r][2] * xt[1][c][2] + xr[0][r][3] * xt[1][c][3];
        float aT = ahat_of(upT);
        float a = a1r[k][q];
        rs += 0.5f * (a * a + aT * aT) * mm;
      }
      *reinterpret_cast<float4*>(w + off) = make_float4(wv[0], wv[1], wv[2], wv[3]);
      rs += __shfl_xor(rs, 1); rs += __shfl_xor(rs, 2);
      rs += __shfl_xor(rs, 4); rs += __shfl_xor(rs, 8);
      if (tx == 0) atomicAdd(&rowsum[b * LL + i], rs);
    }
    if (!diag) {
      int i = J * TT + r;
      int jb = I * TT + 4 * tx;
      int off = (b * LL + i) * LL + jb;
      float wv[4];
      float rs = 0.0f;
#pragma unroll
      for (int q = 0; q < 4; ++q) {
        int c = 4 * tx + q;
        int j = I * TT + c;
        float upT = up1[c][r];
        wv[q] = -0.5f * (up2[r][c] + upT);
        int d = i - j; d = d < 0 ? -d : d;
        float mm = (d <= 3) ? 0.0f
                            : xr[1][r][0] * xt[0][c][0] + xr[1][r][1] * xt[0][c][1] +
                                  xr[1][r][2] * xt[0][c][2] + xr[1][r][3] * xt[0][c][3];
        float aT = ahat_of(upT);
        float a = a2r[k][q];
        rs += 0.5f * (a * a + aT * aT) * mm;
      }
      *reinterpret_cast<float4*>(w + off) = make_float4(wv[0], wv[1], wv[2], wv[3]);
      rs += __shfl_xor(rs, 1); rs += __shfl_xor(rs, 2);
      rs += __shfl_xor(rs, 4); rs += __shfl_xor(rs, 8);
      if (tx == 0) atomicAdd(&rowsum[b * LL + i], rs);
    }
  }
}

// ---------------------------------------------------------------------------
// k_c: per-row scalar prep for a step (B*L threads):
//   lmbd update from previous step's row sums (or init at t=0),
//   c = lmbd * sigmoid(2*(rowsum-1)), zero the next-rowsum accumulator.
// ---------------------------------------------------------------------------
__global__ __launch_bounds__(256) void k_c(float* __restrict__ lmbd,
                                           const float* __restrict__ rs,
                                           float* __restrict__ cc,
                                           float* __restrict__ rsn,
                                           float beta_prev, int first) {
  int idx = blockIdx.x * blockDim.x + threadIdx.x;
  if (idx >= BB * LL) return;
  float t = rs[idx] - 1.0f;
  float rel = t > 0.0f ? t : 0.0f;
  float l = first ? rel : lmbd[idx] + beta_prev * rel;
  lmbd[idx] = l;
  cc[idx] = l * sgm(2.0f * t);
  rsn[idx] = 0.0f;
}

// ---------------------------------------------------------------------------
// k_step: one proximal-gradient step. Tile-pair block updates a_hat in place
// (update is elementwise-local), computes a_new = 0.5(ahn^2+ahn^T^2)*m via
// LDS-staged transpose, writes the step's output slice, accumulates row sums.
// ---------------------------------------------------------------------------
__global__ __launch_bounds__(256) void k_step(const float* __restrict__ x,
                                              const float* __restrict__ w,
                                              float* __restrict__ ah,
                                              const float* __restrict__ cvec,
                                              float* __restrict__ rsn,
                                              float* __restrict__ out,
                                              float alpha, float thr) {
  __shared__ float an1[TT][TT + 1];
  __shared__ float an2[TT][TT + 1];
  __shared__ float xr[2][TT][4];
  __shared__ float xt[2][TT][4];
  __shared__ float cI[TT];
  __shared__ float cJ[TT];

  int b = blockIdx.x / NPAIR;
  int p = blockIdx.x % NPAIR;
  int I, J;
  decode_pair(p, I, J);
  bool diag = (I == J);
  int tid = threadIdx.x;
  int tx = tid & 15, ty = tid >> 4;

  if (tid < 128) {
    int which = tid >> 6;
    int r = tid & 63;
    int gi = (which ? J : I) * TT + r;
    const float* xp = x + ((b * LL) + gi) * 4;
    float A = xp[0], U = xp[1], C = xp[2], G = xp[3];
    xr[which][r][0] = A; xr[which][r][1] = U; xr[which][r][2] = C; xr[which][r][3] = G;
    xt[which][r][0] = U; xt[which][r][1] = A + G; xt[which][r][2] = G; xt[which][r][3] = C + U;
  } else {
    int t2 = tid - 128;
    int which = t2 >> 6;
    int r = t2 & 63;
    int gi = (which ? J : I) * TT + r;
    float cv = cvec[b * LL + gi];
    if (which) cJ[r] = cv; else cI[r] = cv;
  }
  __syncthreads();

  float m1[4][4], m2[4][4];

  // phase 1: a_hat update (in place; element-local), new values to LDS
#pragma unroll
  for (int k = 0; k < 4; ++k) {
    int r = ty + 16 * k;
    {
      int i = I * TT + r;
      int jb = J * TT + 4 * tx;
      int off = (b * LL + i) * LL + jb;
      float4 a4 = *reinterpret_cast<const float4*>(ah + off);
      float4 w4 = *reinterpret_cast<const float4*>(w + off);
      float av[4] = {a4.x, a4.y, a4.z, a4.w};
      float wv[4] = {w4.x, w4.y, w4.z, w4.w};
      float ci = cI[r];
      float res[4];
#pragma unroll
      for (int q = 0; q < 4; ++q) {
        int c = 4 * tx + q;
        int j = J * TT + c;
        int d = i - j; d = d < 0 ? -d : d;
        float mm = (d <= 3) ? 0.0f
                            : xr[0][r][0] * xt[1][c][0] + xr[0][r][1] * xt[1][c][1] +
                                  xr[0][r][2] * xt[1][c][2] + xr[0][r][3] * xt[1][c][3];
        m1[k][q] = mm;
        float g = av[q] * mm * (wv[q] + ci + cJ[c]);
        float an = av[q] - alpha * g;
        an = fabsf(an) - thr;
        an = an > 0.0f ? an : 0.0f;
        an = an < 1.0f ? an : 1.0f;
        res[q] = an;
        an1[r][c] = an;
      }
      *reinterpret_cast<float4*>(ah + off) = make_float4(res[0], res[1], res[2], res[3]);
    }
    if (!diag) {
      int i = J * TT + r;
      int jb = I * TT + 4 * tx;
      int off = (b * LL + i) * LL + jb;
      float4 a4 = *reinterpret_cast<const float4*>(ah + off);
      float4 w4 = *reinterpret_cast<const float4*>(w + off);
      float av[4] = {a4.x, a4.y, a4.z, a4.w};
      float wv[4] = {w4.x, w4.y, w4.z, w4.w};
      float ci = cJ[r];
      float res[4];
#pragma unroll
      for (int q = 0; q < 4; ++q) {
        int c = 4 * tx + q;
        int j = I * TT + c;
        int d = i - j; d = d < 0 ? -d : d;
        float mm = (d <= 3) ? 0.0f
                            : xr[1][r][0] * xt[0][c][0] + xr[1][r][1] * xt[0][c][1] +
                                  xr[1][r][2] * xt[0][c][2] + xr[1][r][3] * xt[0][c][3];
        m2[k][q] = mm;
        float g = av[q] * mm * (wv[q] + ci + cI[c]);
        float an = av[q] - alpha * g;
        an = fabsf(an) - thr;
        an = an > 0.0f ? an : 0.0f;
        an = an < 1.0f ? an : 1.0f;
        res[q] = an;
        an2[r][c] = an;
      }
      *reinterpret_cast<float4*>(ah + off) = make_float4(res[0], res[1], res[2], res[3]);
    }
  }
  __syncthreads();

  float (*A2)[TT + 1] = diag ? an1 : an2;

  // phase 2: a_new = 0.5*(ahn^2 + ahn^T^2)*m  -> out slice + row sums
#pragma unroll
  for (int k = 0; k < 4; ++k) {
    int r = ty + 16 * k;
    {
      int i = I * TT + r;
      int jb = J * TT + 4 * tx;
      int off = (b * LL + i) * LL + jb;
      float res[4];
      float rs = 0.0f;
#pragma unroll
      for (int q = 0; q < 4; ++q) {
        int c = 4 * tx + q;
        float a = an1[r][c];
        float bt = A2[c][r];
        float v = 0.5f * (a * a + bt * bt) * m1[k][q];
        res[q] = v;
        rs += v;
      }
      *reinterpret_cast<float4*>(out + off) = make_float4(res[0], res[1], res[2], res[3]);
      rs += __shfl_xor(rs, 1); rs += __shfl_xor(rs, 2);
      rs += __shfl_xor(rs, 4); rs += __shfl_xor(rs, 8);
      if (tx == 0) atomicAdd(&rsn[b * LL + i], rs);
    }
    if (!diag) {
      int i = J * TT + r;
      int jb = I * TT + 4 * tx;
      int off = (b * LL + i) * LL + jb;
      float res[4];
      float rs = 0.0f;
#pragma unroll
      for (int q = 0; q < 4; ++q) {
        int c = 4 * tx + q;
        float a = an2[r][c];
        float bt = an1[c][r];
        float v = 0.5f * (a * a + bt * bt) * m2[k][q];
        res[q] = v;
        rs += v;
      }
      *reinterpret_cast<float4*>(out + off) = make_float4(res[0], res[1], res[2], res[3]);
      rs += __shfl_xor(rs, 1); rs += __shfl_xor(rs, 2);
      rs += __shfl_xor(rs, 4); rs += __shfl_xor(rs, 8);
      if (tx == 0) atomicAdd(&rsn[b * LL + i], rs);
    }
  }
}

// ---------------------------------------------------------------------------
extern "C" void kernel_launch(void* const* d_in, const int* in_sizes, int n_in,
                              void* d_out, int out_size, void* d_ws, size_t ws_size,
                              hipStream_t stream) {
  const float* u = (const float*)d_in[0];
  const float* x = (const float*)d_in[1];
  float* out = (float*)d_out;

  float* ws = (float*)d_ws;
  float* w = ws;                              // [B,L,L]
  float* ah = ws + (size_t)BLL;               // [B,L,L]
  float* rsA = ws + 2 * (size_t)BLL;          // [B,L]
  float* rsB = rsA + BB * LL;                 // [B,L]
  float* cc = rsB + BB * LL;                  // [B,L]
  float* lmbd = cc + BB * LL;                 // [B,L]
  // total ws use: (2*BLL + 4*B*L)*4 bytes ~= 33.7 MB

  hipMemsetAsync(rsA, 0, BB * LL * sizeof(float), stream);

  dim3 grid(BB * NPAIR);  // 576 blocks
  dim3 block(256);
  k_init<<<grid, block, 0, stream>>>(u, x, w, ah, rsA);

  float* ra = rsA;
  float* rb = rsB;
  for (int t = 0; t < TS; ++t) {
    float alpha = 0.01f * powf(0.99f, (float)t);
    float beta_prev = (t > 0) ? 0.1f * powf(0.99f, (float)(t - 1)) : 0.0f;
    k_c<<<dim3((BB * LL + 255) / 256), block, 0, stream>>>(lmbd, ra, cc, rb, beta_prev,
                                                           t == 0 ? 1 : 0);
    k_step<<<grid, block, 0, stream>>>(x, w, ah, cc, rb, out + (size_t)t * BLL, alpha,
                                       alpha * 0.99f);
    float* tmp = ra; ra = rb; rb = tmp;
  }
}